// Round 6
// baseline (9774.516 us; speedup 1.0000x reference)
//
#include <hip/hip_runtime.h>
#include <hip/hip_fp16.h>

// ONLSTM fused 2-layer recurrent kernel for MI355X (gfx950), round 9.
// r8 verdict: cached h-reads + decoupling = neutral (6044 vs 5807). The
// ~23 us/step is exposed latency: 1 WG/CU, VGPR=80 -> ~10 loads in flight
// in the GEMM streams, plus barrier-B's full rendezvous in the serial chain.
// r9 (r8 skeleton, two changes):
//  1. Barrier B = drain + FB store ONLY (no rendezvous). Each wave polls
//     the FB flags it needs at the top of its own GEMM stream, after its
//     flag-independent loads (layer0-kh0: full XP phase first). Layer1
//     polls all 256 flags (covers h0(s-1), h1(s-2), and PART overwrite
//     safety: FB=s implies that WG finished its step s-1 gather).
//  2. 8-deep explicit A-prefetch register pipelines in all GEMM streams
//     (f16x8 p0[8],p1[8], fully unrolled) -> ~16-24 loads in flight.
// Everything else identical to r8 (passed, absmax 0.0039).

typedef _Float16 f16;
typedef _Float16 f16x8 __attribute__((ext_vector_type(8)));
typedef _Float16 f16x2 __attribute__((ext_vector_type(2)));
typedef float f32x4 __attribute__((ext_vector_type(4)));

#define NWG 256
#define AGENT __HIP_MEMORY_SCOPE_AGENT
#define MFMA16 __builtin_amdgcn_mfma_f32_16x16x32_f16

// ---------------- pack kernels (unchanged, verified) ----------------
__global__ void onlstm_pack_w(const float* __restrict__ W, f16* __restrict__ dst,
                              int nkt, int krow0) {
    int idx = blockIdx.x * blockDim.x + threadIdx.x;
    int total = 128 * 3 * nkt * 64;
    if (idx >= total) return;
    int lane = idx & 63;
    int kt = (idx >> 6) % nkt;
    int ct = ((idx >> 6) / nkt) % 3;
    int w  = (idx >> 6) / (nkt * 3);
    int cc = lane & 15;
    int gate = 2 * ct + (cc >> 3);
    int col = gate * 1024 + (w << 3) + (cc & 7);
    int krow = krow0 + kt * 32 + ((lane >> 4) << 3);
    const float* src = W + (size_t)krow * 6144 + col;
    f16x8 v;
#pragma unroll
    for (int i = 0; i < 8; ++i) v[i] = (f16)src[(size_t)i * 6144];
    *(f16x8*)(dst + (size_t)idx * 8) = v;
}

__global__ void onlstm_pack_x(const float* __restrict__ x, f16* __restrict__ dst) {
    int idx = blockIdx.x * blockDim.x + threadIdx.x;
    if (idx >= 256 * 16 * 4 * 64) return;
    int lane = idx & 63;
    int rt = (idx >> 6) & 3;
    int kt = (idx >> 8) & 15;
    int t  = idx >> 12;
    int m = rt * 16 + (lane & 15);
    int k = kt * 32 + ((lane >> 4) << 3);
    const float* src = x + ((size_t)t * 64 + m) * 512 + k;
    f16x8 v;
#pragma unroll
    for (int i = 0; i < 8; ++i) v[i] = (f16)src[i];
    *(f16x8*)(dst + (size_t)idx * 8) = v;
}

__device__ __forceinline__ float fast_sigmoid(float x) {
    return 1.0f / (1.0f + __expf(-x));
}
__device__ __forceinline__ float fast_tanh(float x) {
    return 1.0f - 2.0f / (__expf(2.0f * x) + 1.0f);
}

// per-wave flag poll: lane l covers flags {l, l+64, ...}; compiler fence after.
__device__ __forceinline__ void poll_flags(const int* base, int cnt, int lane, int tgt) {
#pragma unroll 1
    for (int i = lane; i < cnt; i += 64) {
        const int* fp = base + (size_t)i * 16;
        while (__hip_atomic_load(fp, __ATOMIC_RELAXED, AGENT) < tgt) {}
    }
    asm volatile("" ::: "memory");
}

// ---------------- main persistent kernel ----------------
// LDS: sB 147456 | sZ 64x49 f32 12544 | sPfx 2048 | sScl 1024 | sBias 256
__global__ __launch_bounds__(256, 1) void onlstm_main(
    const f16* __restrict__ WB0, const f16* __restrict__ WB1,
    const f16* __restrict__ WS1, const f16* __restrict__ XP,
    f16* __restrict__ H0P, f16* __restrict__ H1P,
    float* __restrict__ PART, int* __restrict__ FLAGS,
    const float* __restrict__ b0, const float* __restrict__ b1,
    float* __restrict__ out)
{
    extern __shared__ char smem[];
    f16*   sB    = (f16*)smem;
    float* sZ    = (float*)(smem + 147456);
    float* sPfx  = (float*)(smem + 160000);
    float* sScl  = (float*)(smem + 162048);
    float* sBias = (float*)(smem + 163072);

    const int tid = threadIdx.x;
    const int wg = blockIdx.x;
    const int layer = wg >> 7;
    const int w = wg & 127;
    const int lane = tid & 63;
    const int wv = tid >> 6;          // 0..3
    const int rtp = wv & 1;           // row-pair
    const int kh = wv >> 1;           // K-half
    const int j0 = w << 3;
    const int m_u = tid & 63;
    const int pr4 = tid >> 6;
    int* FA = FLAGS;                  // barrier-A flags, stride 16 ints (64B)
    int* FB = FLAGS + 4096;           // barrier-B flags

    // resident weights -> LDS (pre-kernel data: normal cached loads are safe)
    {
        const float4* s4 = (const float4*)(layer ? (WB1 + (size_t)w * (3 * 32 * 512))
                                                 : (WB0 + (size_t)w * (3 * 48 * 512)));
        float4* d4 = (float4*)sB;
        const int n = layer ? (3 * 32 * 64) : (3 * 48 * 64);
        for (int i = tid; i < n; i += 256) d4[i] = s4[i];
    }
    if (tid < 48) {
        int ct = tid >> 4, r = tid & 15;
        int gate = 2 * ct + (r >> 3);
        sBias[tid] = (layer ? b1 : b0)[gate * 1024 + j0 + (r & 7)];
    }
    float c0 = 0.f, c1 = 0.f;   // persistent cell state: (m_u, j0 + pr4*2 + {0,1})
    __syncthreads();

    for (int s = 0; s <= 256; ++s) {
        const int active = layer ? (s >= 1) : (s < 256);
        const int t = layer ? (s - 1) : s;

        if (active) {
            // init sZ with bias
            int m = tid >> 2, cb = (tid & 3) * 12;
            float* dst = sZ + m * 49 + cb;
            const float* bsrc = sBias + cb;
#pragma unroll
            for (int k = 0; k < 12; ++k) dst[k] = bsrc[k];
        }
        __syncthreads();

        if (active) {
            // ---------- GEMM (K-split across wave pairs; per-wave flag gating) ----------
            f32x4 acc[2][3];
#pragma unroll
            for (int r = 0; r < 2; ++r)
#pragma unroll
                for (int c = 0; c < 3; ++c) { f32x4 z = {0.f,0.f,0.f,0.f}; acc[r][c] = z; }

            // h0(s-1) lives at fresh slot s (slot 0 = initial zeros)
            const f16* h0r = H0P + (size_t)s * 65536;
            const int abase = rtp * 1024 + lane * 8;

            if (layer == 0) {
                if (kh == 0) {
                    // XP phase first: independent of flags (hides the poll)
                    const f16* A1 = XP + (size_t)t * 32768;
#pragma unroll 8
                    for (int kt = 0; kt < 16; ++kt) {
                        const f16* ap = A1 + (size_t)kt * 2048 + abase;
                        f16x8 a0 = *(const f16x8*)ap;
                        f16x8 a1 = *(const f16x8*)(ap + 512);
#pragma unroll
                        for (int ct = 0; ct < 3; ++ct) {
                            f16x8 b = *(const f16x8*)(sB + ((size_t)(ct * 48 + kt) * 64 + lane) * 8);
                            acc[0][ct] = MFMA16(a0, b, acc[0][ct], 0, 0, 0);
                            acc[1][ct] = MFMA16(a1, b, acc[1][ct], 0, 0, 0);
                        }
                    }
                    poll_flags(FB, 128, lane, s);   // h0(s-1) published
                    f16x8 p0[8], p1[8];
#pragma unroll
                    for (int k = 0; k < 8; ++k) {
                        const f16* ap = h0r + (size_t)k * 2048 + abase;
                        p0[k] = *(const f16x8*)ap;
                        p1[k] = *(const f16x8*)(ap + 512);
                    }
#pragma unroll
                    for (int k = 0; k < 8; ++k) {
#pragma unroll
                        for (int ct = 0; ct < 3; ++ct) {
                            f16x8 b = *(const f16x8*)(sB + ((size_t)(ct * 48 + 16 + k) * 64 + lane) * 8);
                            acc[0][ct] = MFMA16(p0[k], b, acc[0][ct], 0, 0, 0);
                            acc[1][ct] = MFMA16(p1[k], b, acc[1][ct], 0, 0, 0);
                        }
                    }
                } else {
                    poll_flags(FB, 128, lane, s);   // h0(s-1) published
                    f16x8 p0[8], p1[8];
#pragma unroll
                    for (int k = 0; k < 8; ++k) {
                        const f16* ap = h0r + (size_t)(8 + k) * 2048 + abase;
                        p0[k] = *(const f16x8*)ap;
                        p1[k] = *(const f16x8*)(ap + 512);
                    }
#pragma unroll
                    for (int c = 0; c < 3; ++c) {
#pragma unroll
                        for (int k = 0; k < 8; ++k) {
                            const int kt = 8 + c * 8 + k;   // h-tile index 8..31
                            f16x8 a0 = p0[k], a1 = p1[k];
                            if (c < 2) {
                                const f16* ap = h0r + (size_t)(kt + 8) * 2048 + abase;
                                p0[k] = *(const f16x8*)ap;
                                p1[k] = *(const f16x8*)(ap + 512);
                            }
#pragma unroll
                            for (int ct = 0; ct < 3; ++ct) {
                                f16x8 b = *(const f16x8*)(sB + ((size_t)(ct * 48 + 16 + kt) * 64 + lane) * 8);
                                acc[0][ct] = MFMA16(a0, b, acc[0][ct], 0, 0, 0);
                                acc[1][ct] = MFMA16(a1, b, acc[1][ct], 0, 0, 0);
                            }
                        }
                    }
                }
            } else {
                // layer1: poll all 256 flags (h0(s-1) from layer0, h1(s-2) +
                // PART-overwrite safety from own layer).
                poll_flags(FB, 256, lane, s);
                if (kh == 0) {
                    const f16* BS = WS1 + (size_t)w * (3 * 32 * 512);  // L2-hot weights
                    f16x8 p0[8], p1[8];
#pragma unroll
                    for (int k = 0; k < 8; ++k) {
                        const f16* ap = h0r + (size_t)k * 2048 + abase;
                        p0[k] = *(const f16x8*)ap;
                        p1[k] = *(const f16x8*)(ap + 512);
                    }
#pragma unroll
                    for (int c = 0; c < 4; ++c) {
#pragma unroll
                        for (int k = 0; k < 8; ++k) {
                            const int kt = c * 8 + k;
                            f16x8 a0 = p0[k], a1 = p1[k];
                            if (c < 3) {
                                const f16* ap = h0r + (size_t)(kt + 8) * 2048 + abase;
                                p0[k] = *(const f16x8*)ap;
                                p1[k] = *(const f16x8*)(ap + 512);
                            }
#pragma unroll
                            for (int ct = 0; ct < 3; ++ct) {
                                f16x8 b = *(const f16x8*)(BS + ((size_t)(ct * 32 + kt) * 64 + lane) * 8);
                                acc[0][ct] = MFMA16(a0, b, acc[0][ct], 0, 0, 0);
                                acc[1][ct] = MFMA16(a1, b, acc[1][ct], 0, 0, 0);
                            }
                        }
                    }
                } else {
                    // h1(s-2) lives at fresh slot s-1 (slot 0 = initial zeros)
                    const f16* h1r = H1P + (size_t)(s - 1) * 65536;
                    f16x8 p0[8], p1[8];
#pragma unroll
                    for (int k = 0; k < 8; ++k) {
                        const f16* ap = h1r + (size_t)k * 2048 + abase;
                        p0[k] = *(const f16x8*)ap;
                        p1[k] = *(const f16x8*)(ap + 512);
                    }
#pragma unroll
                    for (int c = 0; c < 4; ++c) {
#pragma unroll
                        for (int k = 0; k < 8; ++k) {
                            const int kt = c * 8 + k;
                            f16x8 a0 = p0[k], a1 = p1[k];
                            if (c < 3) {
                                const f16* ap = h1r + (size_t)(kt + 8) * 2048 + abase;
                                p0[k] = *(const f16x8*)ap;
                                p1[k] = *(const f16x8*)(ap + 512);
                            }
#pragma unroll
                            for (int ct = 0; ct < 3; ++ct) {
                                f16x8 b = *(const f16x8*)(sB + ((size_t)(ct * 32 + kt) * 64 + lane) * 8);
                                acc[0][ct] = MFMA16(a0, b, acc[0][ct], 0, 0, 0);
                                acc[1][ct] = MFMA16(a1, b, acc[1][ct], 0, 0, 0);
                            }
                        }
                    }
                }
            }
            // epilogue: accumulate partials into sZ (bias pre-loaded)
            const int mq = ((lane >> 4) << 2);
            const int colb = lane & 15;
#pragma unroll
            for (int r = 0; r < 2; ++r) {
                int mrow = rtp * 32 + r * 16 + mq;
#pragma unroll
                for (int ct = 0; ct < 3; ++ct) {
                    int col = ct * 16 + colb;
#pragma unroll
                    for (int q = 0; q < 4; ++q)
                        atomicAdd(&sZ[(mrow + q) * 49 + col], acc[r][ct][q]);
                }
            }
        }
        __syncthreads();

        if (active && tid < 128) {
            // local scan: exp + inclusive cumsum over 8 cols (g = f~ or i~)
            int g = tid >> 6, m = tid & 63;
            float run = 0.f;
            float* zp = sZ + m * 49 + 32 + g * 8;
#pragma unroll
            for (int jj = 0; jj < 8; ++jj) {
                float e = __expf(zp[jj]);
                run += e;
                zp[jj] = run;
            }
            __hip_atomic_store(&PART[((size_t)(layer * 2 + g) * 128 + w) * 64 + m], run,
                               __ATOMIC_RELAXED, AGENT);
        }

        // ---------- barrier A (layer-local, flag array, r3-proven) ----------
        __syncthreads();   // implicit vmcnt(0): all waves' sc1 stores at coherence point
        if (tid == 0)
            __hip_atomic_store(&FA[wg * 16], s + 1, __ATOMIC_RELAXED, AGENT);
        if (tid < 128) {
            const int* fp = &FA[(layer * 128 + tid) * 16];
            while (__hip_atomic_load(fp, __ATOMIC_RELAXED, AGENT) < s + 1) {}
        }
        asm volatile("" ::: "memory");
        __syncthreads();

        if (active) {
            // global prefix/total, half-split across the 4 waves (sc1 loads)
            int g = pr4 & 1, half = pr4 >> 1;
            const float* pp = PART + ((size_t)(layer * 2 + g) * 128 + half * 64) * 64 + m_u;
            float pref = 0.f, tot = 0.f;
            int wrel = w - half * 64;
#pragma unroll 16
            for (int w2 = 0; w2 < 64; ++w2) {
                float v = __hip_atomic_load(&pp[(size_t)w2 * 64], __ATOMIC_RELAXED, AGENT);
                tot += v;
                pref += (w2 < wrel) ? v : 0.f;
            }
            float* q = sPfx + ((size_t)(m_u * 2 + g) * 2 + half) * 2;
            q[0] = pref; q[1] = tot;
        }
        __syncthreads();
        if (active && tid < 128) {
            int g = tid >> 6, m = tid & 63;
            float* q = sPfx + (size_t)(m * 2 + g) * 4;
            sScl[m * 4 + g * 2]     = q[0] + q[2];
            sScl[m * 4 + g * 2 + 1] = 1.0f / (q[1] + q[3]);
        }
        __syncthreads();

        if (active) {
            // ---------- gate math + state update (2 cols/thread) ----------
            float pf = sScl[m_u * 4 + 0], rf = sScl[m_u * 4 + 1];
            float pi = sScl[m_u * 4 + 2], ri = sScl[m_u * 4 + 3];
            int zb = m_u * 49;
            float cc[2] = {c0, c1}, hh[2];
#pragma unroll
            for (int q = 0; q < 2; ++q) {
                int jj = pr4 * 2 + q;
                float zi = sZ[zb + jj];
                float zf = sZ[zb + 8 + jj];
                float zg = sZ[zb + 16 + jj];
                float zo = sZ[zb + 24 + jj];
                float cft = sZ[zb + 32 + jj];
                float cit = sZ[zb + 40 + jj];
                float ftil = (pf + cft) * rf;
                float itil = 1.0f - (pi + cit) * ri;
                float om = ftil * itil;
                float fi = fast_sigmoid(zf);
                float ii = fast_sigmoid(zi);
                float oo = fast_sigmoid(zo);
                float ch = fast_tanh(zg);
                float fh = fi * om + (ftil - om);
                float ih = ii * om + (itil - om);
                float cn = fh * cc[q] + ih * ch;
                cc[q] = cn;
                hh[q] = oo * fast_tanh(cn);
            }
            c0 = cc[0]; c1 = cc[1];

            // publish h as A-fragments (fp16, sc1 write-through to fresh slot)
            int jfull = j0 + pr4 * 2;
            int ktp = jfull >> 5;
            int quad = (jfull >> 3) & 3;
            int i0 = jfull & 7;
            f16* HP = layer ? (H1P + (size_t)s * 65536)        // h1(s-1) -> slot s
                            : (H0P + (size_t)(s + 1) * 65536); // h0(s)   -> slot s+1
            union { f16x2 h; int i; } hu;
            hu.h[0] = (f16)hh[0]; hu.h[1] = (f16)hh[1];
            __hip_atomic_store(
                (int*)(HP + ((size_t)(ktp * 4 + (m_u >> 4)) * 64 + (quad * 16 + (m_u & 15))) * 8 + i0),
                hu.i, __ATOMIC_RELAXED, AGENT);

            if (layer)
                *(float2*)(out + (size_t)t * 65536 + (size_t)m_u * 1024 + jfull) = make_float2(hh[0], hh[1]);
            if (t == 255) {
                *(float2*)(out + 16777216 + (size_t)layer * 65536 + (size_t)m_u * 1024 + jfull) = make_float2(hh[0], hh[1]);
                *(float2*)(out + 16908288 + (size_t)layer * 65536 + (size_t)m_u * 1024 + jfull) = make_float2(cc[0], cc[1]);
            }
        }

        // ---------- barrier B: drain + publish ONLY (no rendezvous) ----------
        if (s < 256) {
            __syncthreads();   // drains all waves' h sc1 stores; separates sZ reuse
            if (tid == 0)
                __hip_atomic_store(&FB[wg * 16], s + 1, __ATOMIC_RELAXED, AGENT);
        }
    }
}

// ---------------- launch ----------------
extern "C" void kernel_launch(void* const* d_in, const int* in_sizes, int n_in,
                              void* d_out, int out_size, void* d_ws, size_t ws_size,
                              hipStream_t stream) {
    const float* x  = (const float*)d_in[0];
    const float* W0 = (const float*)d_in[1];
    const float* b0 = (const float*)d_in[2];
    const float* W1 = (const float*)d_in[3];
    const float* b1 = (const float*)d_in[4];
    float* out = (float*)d_out;

    char* ws = (char*)d_ws;
    f16* WB0    = (f16*)(ws + 0);           // 18874368
    f16* WB1    = (f16*)(ws + 18874368);    // 12582912
    f16* WS1    = (f16*)(ws + 31457280);    // 12582912
    f16* XP     = (f16*)(ws + 44040192);    // 16777216
    f16* H0P    = (f16*)(ws + 60817408);    // 257 x 131072 = 33685504
    f16* H1P    = (f16*)(ws + 94502912);    // 257 x 131072 = 33685504
    float* PART = (float*)(ws + 128188416); // 131072
    int* FLAGS  = (int*)(ws + 128319488);   // 32768  (total 128352256 B)

    hipMemsetAsync(H0P, 0, 131072, stream);   // slot 0 = h0(-1) = 0
    hipMemsetAsync(H1P, 0, 131072, stream);   // slot 0 = h1(-1) = 0
    hipMemsetAsync(FLAGS, 0, 32768, stream);

    {   int n = 128 * 3 * 48 * 64;
        onlstm_pack_w<<<(n + 255) / 256, 256, 0, stream>>>(W0, WB0, 48, 0); }
    {   int n = 128 * 3 * 32 * 64;
        onlstm_pack_w<<<(n + 255) / 256, 256, 0, stream>>>(W1, WB1, 32, 1024); }
    {   int n = 128 * 3 * 32 * 64;
        onlstm_pack_w<<<(n + 255) / 256, 256, 0, stream>>>(W1, WS1, 32, 0); }
    {   int n = 256 * 16 * 4 * 64;
        onlstm_pack_x<<<(n + 255) / 256, 256, 0, stream>>>(x, XP); }

    const int smem_bytes = 163328;
    hipFuncSetAttribute((const void*)onlstm_main,
                        hipFuncAttributeMaxDynamicSharedMemorySize, smem_bytes);
    onlstm_main<<<NWG, 256, smem_bytes, stream>>>(WB0, WB1, WS1, XP, H0P, H1P,
                                                  PART, FLAGS, b0, b1, out);
}

// Round 7
// 5852.388 us; speedup vs baseline: 1.6702x; 1.6702x over previous
//
#include <hip/hip_runtime.h>
#include <hip/hip_fp16.h>

// ONLSTM fused 2-layer recurrent kernel for MI355X (gfx950), round 10.
// REVERT to the measured-best r3 structure (5807-5920 us). Session ledger:
//   r5 counter-barrier + cached reads: +14% (128 same-line RMWs serialize)
//   r6 64 fat WGs + streamed weights:  4.2x worse (latency-bound streaming)
//   r8 cached fresh-slot h reads:      neutral (h read path not the cost)
//   r9 rendezvous removal + prefetch:  +60% (spin-polls interleaved with
//      GEMM loads congest the fabric; polls are only safe at quiescent
//      rendezvous points, where r3 already has them)
// The regime is a synchronization-latency floor (VALU+MFMA <6%, HBM 2%,
// 1 wave/SIMD); r3's arrangement is the empirical local optimum.
// Single change vs r3: PART-gather unroll 16 -> 32 (halves the serial
// batch count of the 64 coherent loads on the inter-barrier chain).

typedef _Float16 f16;
typedef _Float16 f16x8 __attribute__((ext_vector_type(8)));
typedef _Float16 f16x2 __attribute__((ext_vector_type(2)));
typedef float f32x4 __attribute__((ext_vector_type(4)));

#define NWG 256
#define AGENT __HIP_MEMORY_SCOPE_AGENT

// coherent (sc1) 16B fragment load: two relaxed agent-scope u64 atomic loads
__device__ __forceinline__ f16x8 ld_frag(const f16* p) {
    union { unsigned long long u[2]; f16x8 v; } c;
    c.u[0] = __hip_atomic_load((const unsigned long long*)p, __ATOMIC_RELAXED, AGENT);
    c.u[1] = __hip_atomic_load(((const unsigned long long*)p) + 1, __ATOMIC_RELAXED, AGENT);
    return c.v;
}

// ---------------- pack kernels (unchanged, verified) ----------------
__global__ void onlstm_pack_w(const float* __restrict__ W, f16* __restrict__ dst,
                              int nkt, int krow0) {
    int idx = blockIdx.x * blockDim.x + threadIdx.x;
    int total = 128 * 3 * nkt * 64;
    if (idx >= total) return;
    int lane = idx & 63;
    int kt = (idx >> 6) % nkt;
    int ct = ((idx >> 6) / nkt) % 3;
    int w  = (idx >> 6) / (nkt * 3);
    int cc = lane & 15;
    int gate = 2 * ct + (cc >> 3);
    int col = gate * 1024 + (w << 3) + (cc & 7);
    int krow = krow0 + kt * 32 + ((lane >> 4) << 3);
    const float* src = W + (size_t)krow * 6144 + col;
    f16x8 v;
#pragma unroll
    for (int i = 0; i < 8; ++i) v[i] = (f16)src[(size_t)i * 6144];
    *(f16x8*)(dst + (size_t)idx * 8) = v;
}

__global__ void onlstm_pack_x(const float* __restrict__ x, f16* __restrict__ dst) {
    int idx = blockIdx.x * blockDim.x + threadIdx.x;
    if (idx >= 256 * 16 * 4 * 64) return;
    int lane = idx & 63;
    int rt = (idx >> 6) & 3;
    int kt = (idx >> 8) & 15;
    int t  = idx >> 12;
    int m = rt * 16 + (lane & 15);
    int k = kt * 32 + ((lane >> 4) << 3);
    const float* src = x + ((size_t)t * 64 + m) * 512 + k;
    f16x8 v;
#pragma unroll
    for (int i = 0; i < 8; ++i) v[i] = (f16)src[i];
    *(f16x8*)(dst + (size_t)idx * 8) = v;
}

__device__ __forceinline__ float fast_sigmoid(float x) {
    return 1.0f / (1.0f + __expf(-x));
}
__device__ __forceinline__ float fast_tanh(float x) {
    return 1.0f - 2.0f / (__expf(2.0f * x) + 1.0f);
}

// ---------------- main persistent kernel ----------------
// LDS: sB 147456 | sZ 64x49 f32 12544 | sPfx 2048 | sScl 1024 | sBias 256
__global__ __launch_bounds__(256, 1) void onlstm_main(
    const f16* __restrict__ WB0, const f16* __restrict__ WB1,
    const f16* __restrict__ WS1, const f16* __restrict__ XP,
    f16* __restrict__ H0P, f16* __restrict__ H1P,
    float* __restrict__ PART, int* __restrict__ FLAGS,
    const float* __restrict__ b0, const float* __restrict__ b1,
    float* __restrict__ out)
{
    extern __shared__ char smem[];
    f16*   sB    = (f16*)smem;
    float* sZ    = (float*)(smem + 147456);
    float* sPfx  = (float*)(smem + 160000);
    float* sScl  = (float*)(smem + 162048);
    float* sBias = (float*)(smem + 163072);

    const int tid = threadIdx.x;
    const int wg = blockIdx.x;
    const int layer = wg >> 7;
    const int w = wg & 127;
    const int lane = tid & 63;
    const int wv = tid >> 6;          // 0..3
    const int rtp = wv & 1;           // row-pair
    const int kh = wv >> 1;           // K-half
    const int j0 = w << 3;
    const int m_u = tid & 63;
    const int pr4 = tid >> 6;
    int* FA = FLAGS;                  // barrier-A flags, stride 16 ints (64B)
    int* FB = FLAGS + 4096;           // barrier-B flags

    // resident weights -> LDS (pre-kernel data: normal cached loads are safe)
    {
        const float4* s4 = (const float4*)(layer ? (WB1 + (size_t)w * (3 * 32 * 512))
                                                 : (WB0 + (size_t)w * (3 * 48 * 512)));
        float4* d4 = (float4*)sB;
        const int n = layer ? (3 * 32 * 64) : (3 * 48 * 64);
        for (int i = tid; i < n; i += 256) d4[i] = s4[i];
    }
    if (tid < 48) {
        int ct = tid >> 4, r = tid & 15;
        int gate = 2 * ct + (r >> 3);
        sBias[tid] = (layer ? b1 : b0)[gate * 1024 + j0 + (r & 7)];
    }
    float c0 = 0.f, c1 = 0.f;   // persistent cell state: (m_u, j0 + pr4*2 + {0,1})
    __syncthreads();

    for (int s = 0; s <= 256; ++s) {
        const int active = layer ? (s >= 1) : (s < 256);
        const int t = layer ? (s - 1) : s;
        const int hr = (s + 2) % 3;               // H0 read slot = h0(s-1)

        if (active) {
            // init sZ with bias
            int m = tid >> 2, cb = (tid & 3) * 12;
            float* dst = sZ + m * 49 + cb;
            const float* bsrc = sBias + cb;
#pragma unroll
            for (int k = 0; k < 12; ++k) dst[k] = bsrc[k];
        }
        __syncthreads();

        if (active) {
            // ---------- GEMM (K-split across wave pairs) ----------
            f32x4 acc[2][3];
#pragma unroll
            for (int r = 0; r < 2; ++r)
#pragma unroll
                for (int c = 0; c < 3; ++c) { f32x4 z = {0.f,0.f,0.f,0.f}; acc[r][c] = z; }

            const f16* h0r = H0P + (size_t)hr * 65536;
            const int abase = rtp * 1024 + lane * 8;

            if (layer == 0) {
                if (kh == 0) {
                    const f16* A1 = XP + (size_t)t * 32768;
#pragma unroll 8
                    for (int kt = 0; kt < 16; ++kt) {
                        const f16* ap = A1 + (size_t)kt * 2048 + abase;
                        f16x8 a0 = *(const f16x8*)ap;          // XP: pre-kernel, cached
                        f16x8 a1 = *(const f16x8*)(ap + 512);
#pragma unroll
                        for (int ct = 0; ct < 3; ++ct) {
                            f16x8 b = *(const f16x8*)(sB + ((size_t)(ct * 48 + kt) * 64 + lane) * 8);
                            acc[0][ct] = __builtin_amdgcn_mfma_f32_16x16x32_f16(a0, b, acc[0][ct], 0, 0, 0);
                            acc[1][ct] = __builtin_amdgcn_mfma_f32_16x16x32_f16(a1, b, acc[1][ct], 0, 0, 0);
                        }
                    }
#pragma unroll 8
                    for (int kt = 0; kt < 8; ++kt) {
                        const f16* ap = h0r + (size_t)kt * 2048 + abase;
                        f16x8 a0 = ld_frag(ap);                // H: intra-kernel, sc1
                        f16x8 a1 = ld_frag(ap + 512);
#pragma unroll
                        for (int ct = 0; ct < 3; ++ct) {
                            f16x8 b = *(const f16x8*)(sB + ((size_t)(ct * 48 + 16 + kt) * 64 + lane) * 8);
                            acc[0][ct] = __builtin_amdgcn_mfma_f32_16x16x32_f16(a0, b, acc[0][ct], 0, 0, 0);
                            acc[1][ct] = __builtin_amdgcn_mfma_f32_16x16x32_f16(a1, b, acc[1][ct], 0, 0, 0);
                        }
                    }
                } else {
#pragma unroll 8
                    for (int kt = 8; kt < 32; ++kt) {
                        const f16* ap = h0r + (size_t)kt * 2048 + abase;
                        f16x8 a0 = ld_frag(ap);
                        f16x8 a1 = ld_frag(ap + 512);
#pragma unroll
                        for (int ct = 0; ct < 3; ++ct) {
                            f16x8 b = *(const f16x8*)(sB + ((size_t)(ct * 48 + 16 + kt) * 64 + lane) * 8);
                            acc[0][ct] = __builtin_amdgcn_mfma_f32_16x16x32_f16(a0, b, acc[0][ct], 0, 0, 0);
                            acc[1][ct] = __builtin_amdgcn_mfma_f32_16x16x32_f16(a1, b, acc[1][ct], 0, 0, 0);
                        }
                    }
                }
            } else {
                if (kh == 0) {
                    const f16* BS = WS1 + (size_t)w * (3 * 32 * 512);  // pre-kernel, cached
#pragma unroll 8
                    for (int kt = 0; kt < 32; ++kt) {
                        const f16* ap = h0r + (size_t)kt * 2048 + abase;
                        f16x8 a0 = ld_frag(ap);
                        f16x8 a1 = ld_frag(ap + 512);
#pragma unroll
                        for (int ct = 0; ct < 3; ++ct) {
                            f16x8 b = *(const f16x8*)(BS + ((size_t)(ct * 32 + kt) * 64 + lane) * 8);
                            acc[0][ct] = __builtin_amdgcn_mfma_f32_16x16x32_f16(a0, b, acc[0][ct], 0, 0, 0);
                            acc[1][ct] = __builtin_amdgcn_mfma_f32_16x16x32_f16(a1, b, acc[1][ct], 0, 0, 0);
                        }
                    }
                } else {
                    const f16* h1r = H1P + (size_t)(s & 1) * 65536;    // h1(s-2)
#pragma unroll 8
                    for (int kt = 0; kt < 32; ++kt) {
                        const f16* ap = h1r + (size_t)kt * 2048 + abase;
                        f16x8 a0 = ld_frag(ap);
                        f16x8 a1 = ld_frag(ap + 512);
#pragma unroll
                        for (int ct = 0; ct < 3; ++ct) {
                            f16x8 b = *(const f16x8*)(sB + ((size_t)(ct * 32 + kt) * 64 + lane) * 8);
                            acc[0][ct] = __builtin_amdgcn_mfma_f32_16x16x32_f16(a0, b, acc[0][ct], 0, 0, 0);
                            acc[1][ct] = __builtin_amdgcn_mfma_f32_16x16x32_f16(a1, b, acc[1][ct], 0, 0, 0);
                        }
                    }
                }
            }
            // epilogue: accumulate partials into sZ (bias pre-loaded)
            const int mq = ((lane >> 4) << 2);
            const int colb = lane & 15;
#pragma unroll
            for (int r = 0; r < 2; ++r) {
                int mrow = rtp * 32 + r * 16 + mq;
#pragma unroll
                for (int ct = 0; ct < 3; ++ct) {
                    int col = ct * 16 + colb;
#pragma unroll
                    for (int q = 0; q < 4; ++q)
                        atomicAdd(&sZ[(mrow + q) * 49 + col], acc[r][ct][q]);
                }
            }
        }
        __syncthreads();

        if (active && tid < 128) {
            // local scan: exp + inclusive cumsum over 8 cols (g = f~ or i~)
            int g = tid >> 6, m = tid & 63;
            float run = 0.f;
            float* zp = sZ + m * 49 + 32 + g * 8;
#pragma unroll
            for (int jj = 0; jj < 8; ++jj) {
                float e = __expf(zp[jj]);
                run += e;
                zp[jj] = run;
            }
            __hip_atomic_store(&PART[((size_t)(layer * 2 + g) * 128 + w) * 64 + m], run,
                               __ATOMIC_RELAXED, AGENT);
        }

        // ---------- barrier A (layer-local, flag-based, fence-free) ----------
        __syncthreads();   // implicit vmcnt(0): all waves' sc1 stores at coherence point
        if (tid == 0)
            __hip_atomic_store(&FA[wg * 16], s + 1, __ATOMIC_RELAXED, AGENT);
        if (tid < 128) {
            const int* fp = &FA[(layer * 128 + tid) * 16];
            while (__hip_atomic_load(fp, __ATOMIC_RELAXED, AGENT) < s + 1) {}
        }
        __syncthreads();

        if (active) {
            // global prefix/total, half-split across the 4 waves (sc1 loads)
            int g = pr4 & 1, half = pr4 >> 1;
            const float* pp = PART + ((size_t)(layer * 2 + g) * 128 + half * 64) * 64 + m_u;
            float pref = 0.f, tot = 0.f;
            int wrel = w - half * 64;
#pragma unroll 32
            for (int w2 = 0; w2 < 64; ++w2) {
                float v = __hip_atomic_load(&pp[(size_t)w2 * 64], __ATOMIC_RELAXED, AGENT);
                tot += v;
                pref += (w2 < wrel) ? v : 0.f;
            }
            float* q = sPfx + ((size_t)(m_u * 2 + g) * 2 + half) * 2;
            q[0] = pref; q[1] = tot;
        }
        __syncthreads();
        if (active && tid < 128) {
            int g = tid >> 6, m = tid & 63;
            float* q = sPfx + (size_t)(m * 2 + g) * 4;
            sScl[m * 4 + g * 2]     = q[0] + q[2];
            sScl[m * 4 + g * 2 + 1] = 1.0f / (q[1] + q[3]);
        }
        __syncthreads();

        if (active) {
            // ---------- gate math + state update (2 cols/thread) ----------
            float pf = sScl[m_u * 4 + 0], rf = sScl[m_u * 4 + 1];
            float pi = sScl[m_u * 4 + 2], ri = sScl[m_u * 4 + 3];
            int zb = m_u * 49;
            float cc[2] = {c0, c1}, hh[2];
#pragma unroll
            for (int q = 0; q < 2; ++q) {
                int jj = pr4 * 2 + q;
                float zi = sZ[zb + jj];
                float zf = sZ[zb + 8 + jj];
                float zg = sZ[zb + 16 + jj];
                float zo = sZ[zb + 24 + jj];
                float cft = sZ[zb + 32 + jj];
                float cit = sZ[zb + 40 + jj];
                float ftil = (pf + cft) * rf;
                float itil = 1.0f - (pi + cit) * ri;
                float om = ftil * itil;
                float fi = fast_sigmoid(zf);
                float ii = fast_sigmoid(zi);
                float oo = fast_sigmoid(zo);
                float ch = fast_tanh(zg);
                float fh = fi * om + (ftil - om);
                float ih = ii * om + (itil - om);
                float cn = fh * cc[q] + ih * ch;
                cc[q] = cn;
                hh[q] = oo * fast_tanh(cn);
            }
            c0 = cc[0]; c1 = cc[1];

            // publish h as A-fragments (fp16, sc1 write-through)
            int jfull = j0 + pr4 * 2;
            int ktp = jfull >> 5;
            int quad = (jfull >> 3) & 3;
            int i0 = jfull & 7;
            f16* HP = layer ? (H1P + (size_t)((s + 1) & 1) * 65536)
                            : (H0P + (size_t)(s % 3) * 65536);
            union { f16x2 h; int i; } hu;
            hu.h[0] = (f16)hh[0]; hu.h[1] = (f16)hh[1];
            __hip_atomic_store(
                (int*)(HP + ((size_t)(ktp * 4 + (m_u >> 4)) * 64 + (quad * 16 + (m_u & 15))) * 8 + i0),
                hu.i, __ATOMIC_RELAXED, AGENT);

            if (layer)
                *(float2*)(out + (size_t)t * 65536 + (size_t)m_u * 1024 + jfull) = make_float2(hh[0], hh[1]);
            if (t == 255) {
                *(float2*)(out + 16777216 + (size_t)layer * 65536 + (size_t)m_u * 1024 + jfull) = make_float2(hh[0], hh[1]);
                *(float2*)(out + 16908288 + (size_t)layer * 65536 + (size_t)m_u * 1024 + jfull) = make_float2(cc[0], cc[1]);
            }
        }

        // ---------- barrier B (split by layer, pipeline slack, fence-free) ----------
        if (s < 256) {
            __syncthreads();   // drains all waves' h sc1 stores
            if (tid == 0)
                __hip_atomic_store(&FB[wg * 16], s + 1, __ATOMIC_RELAXED, AGENT);
            if (layer == 0) {
                if (tid < 128) {
                    const int* fp = &FB[tid * 16];
                    while (__hip_atomic_load(fp, __ATOMIC_RELAXED, AGENT) < s + 1) {}
                } else {
                    // anti-overwrite: layer1 must have finished GEMM of step s-1
                    const int* fp = &FA[tid * 16];
                    while (__hip_atomic_load(fp, __ATOMIC_RELAXED, AGENT) < s) {}
                }
            } else {
                const int* fp = &FB[tid * 16];
                while (__hip_atomic_load(fp, __ATOMIC_RELAXED, AGENT) < s + 1) {}
            }
            __syncthreads();
        }
    }
}

// ---------------- launch ----------------
extern "C" void kernel_launch(void* const* d_in, const int* in_sizes, int n_in,
                              void* d_out, int out_size, void* d_ws, size_t ws_size,
                              hipStream_t stream) {
    const float* x  = (const float*)d_in[0];
    const float* W0 = (const float*)d_in[1];
    const float* b0 = (const float*)d_in[2];
    const float* W1 = (const float*)d_in[3];
    const float* b1 = (const float*)d_in[4];
    float* out = (float*)d_out;

    char* ws = (char*)d_ws;
    f16* WB0    = (f16*)(ws + 0);           // 18874368
    f16* WB1    = (f16*)(ws + 18874368);    // 12582912
    f16* WS1    = (f16*)(ws + 31457280);    // 12582912
    f16* XP     = (f16*)(ws + 44040192);    // 16777216
    f16* H0P    = (f16*)(ws + 60817408);    // 3 x 131072
    f16* H1P    = (f16*)(ws + 61210624);    // 2 x 131072
    float* PART = (float*)(ws + 61472768);  // 131072
    int* FLAGS  = (int*)(ws + 61603840);    // 32768

    hipMemsetAsync(H0P, 0, 393216, stream);
    hipMemsetAsync(H1P, 0, 262144, stream);
    hipMemsetAsync(FLAGS, 0, 32768, stream);

    {   int n = 128 * 3 * 48 * 64;
        onlstm_pack_w<<<(n + 255) / 256, 256, 0, stream>>>(W0, WB0, 48, 0); }
    {   int n = 128 * 3 * 32 * 64;
        onlstm_pack_w<<<(n + 255) / 256, 256, 0, stream>>>(W1, WB1, 32, 1024); }
    {   int n = 128 * 3 * 32 * 64;
        onlstm_pack_w<<<(n + 255) / 256, 256, 0, stream>>>(W1, WS1, 32, 0); }
    {   int n = 256 * 16 * 4 * 64;
        onlstm_pack_x<<<(n + 255) / 256, 256, 0, stream>>>(x, XP); }

    const int smem_bytes = 163328;
    hipFuncSetAttribute((const void*)onlstm_main,
                        hipFuncAttributeMaxDynamicSharedMemorySize, smem_bytes);
    onlstm_main<<<NWG, 256, smem_bytes, stream>>>(WB0, WB1, WS1, XP, H0P, H1P,
                                                  PART, FLAGS, b0, b1, out);
}

// Round 8
// 4691.048 us; speedup vs baseline: 2.0837x; 1.2476x over previous
//
#include <hip/hip_runtime.h>
#include <hip/hip_fp16.h>

// ONLSTM fused 2-layer recurrent kernel for MI355X (gfx950), round 11.
// Base: r3/r10 skeleton (measured best, 5807-5852 us). Sync semantics
// (flag-array barriers, sc1 h ring exchange, LDS-resident weights, 256 WGs)
// are UNTOUCHED -- every structural change measured worse (r5/r6/r9).
// Two serial-chain shavings inside the skeleton:
//  1. PART fresh-slot per step (257 x 131072 B): writers keep sc1 (drained
//     before FA publish), readers become PLAIN CACHED loads -- same
//     freshness pattern r8 validated for h (cold addresses per dispatch,
//     first miss fills L2 from L3, rest of XCD hits L2). Gather latency
//     ~700cy/load -> ~200cy.
//  2. Epilogue without LDS atomics: kh=1 waves STORE partials, syncthreads,
//     kh=0 waves RMW-add (acc + partial + bias). Bias-init phase deleted
//     (its syncthreads repurposed as the store/RMW separator).

typedef _Float16 f16;
typedef _Float16 f16x8 __attribute__((ext_vector_type(8)));
typedef _Float16 f16x2 __attribute__((ext_vector_type(2)));
typedef float f32x4 __attribute__((ext_vector_type(4)));

#define NWG 256
#define AGENT __HIP_MEMORY_SCOPE_AGENT

// coherent (sc1) 16B fragment load: two relaxed agent-scope u64 atomic loads
__device__ __forceinline__ f16x8 ld_frag(const f16* p) {
    union { unsigned long long u[2]; f16x8 v; } c;
    c.u[0] = __hip_atomic_load((const unsigned long long*)p, __ATOMIC_RELAXED, AGENT);
    c.u[1] = __hip_atomic_load(((const unsigned long long*)p) + 1, __ATOMIC_RELAXED, AGENT);
    return c.v;
}

// ---------------- pack kernels (unchanged, verified) ----------------
__global__ void onlstm_pack_w(const float* __restrict__ W, f16* __restrict__ dst,
                              int nkt, int krow0) {
    int idx = blockIdx.x * blockDim.x + threadIdx.x;
    int total = 128 * 3 * nkt * 64;
    if (idx >= total) return;
    int lane = idx & 63;
    int kt = (idx >> 6) % nkt;
    int ct = ((idx >> 6) / nkt) % 3;
    int w  = (idx >> 6) / (nkt * 3);
    int cc = lane & 15;
    int gate = 2 * ct + (cc >> 3);
    int col = gate * 1024 + (w << 3) + (cc & 7);
    int krow = krow0 + kt * 32 + ((lane >> 4) << 3);
    const float* src = W + (size_t)krow * 6144 + col;
    f16x8 v;
#pragma unroll
    for (int i = 0; i < 8; ++i) v[i] = (f16)src[(size_t)i * 6144];
    *(f16x8*)(dst + (size_t)idx * 8) = v;
}

__global__ void onlstm_pack_x(const float* __restrict__ x, f16* __restrict__ dst) {
    int idx = blockIdx.x * blockDim.x + threadIdx.x;
    if (idx >= 256 * 16 * 4 * 64) return;
    int lane = idx & 63;
    int rt = (idx >> 6) & 3;
    int kt = (idx >> 8) & 15;
    int t  = idx >> 12;
    int m = rt * 16 + (lane & 15);
    int k = kt * 32 + ((lane >> 4) << 3);
    const float* src = x + ((size_t)t * 64 + m) * 512 + k;
    f16x8 v;
#pragma unroll
    for (int i = 0; i < 8; ++i) v[i] = (f16)src[i];
    *(f16x8*)(dst + (size_t)idx * 8) = v;
}

__device__ __forceinline__ float fast_sigmoid(float x) {
    return 1.0f / (1.0f + __expf(-x));
}
__device__ __forceinline__ float fast_tanh(float x) {
    return 1.0f - 2.0f / (__expf(2.0f * x) + 1.0f);
}

// ---------------- main persistent kernel ----------------
// LDS: sB 147456 | sZ 64x49 f32 12544 | sPfx 2048 | sScl 1024 | sBias 256
__global__ __launch_bounds__(256, 1) void onlstm_main(
    const f16* __restrict__ WB0, const f16* __restrict__ WB1,
    const f16* __restrict__ WS1, const f16* __restrict__ XP,
    f16* __restrict__ H0P, f16* __restrict__ H1P,
    float* __restrict__ PARTS, int* __restrict__ FLAGS,
    const float* __restrict__ b0, const float* __restrict__ b1,
    float* __restrict__ out)
{
    extern __shared__ char smem[];
    f16*   sB    = (f16*)smem;
    float* sZ    = (float*)(smem + 147456);
    float* sPfx  = (float*)(smem + 160000);
    float* sScl  = (float*)(smem + 162048);
    float* sBias = (float*)(smem + 163072);

    const int tid = threadIdx.x;
    const int wg = blockIdx.x;
    const int layer = wg >> 7;
    const int w = wg & 127;
    const int lane = tid & 63;
    const int wv = tid >> 6;          // 0..3
    const int rtp = wv & 1;           // row-pair
    const int kh = wv >> 1;           // K-half
    const int j0 = w << 3;
    const int m_u = tid & 63;
    const int pr4 = tid >> 6;
    int* FA = FLAGS;                  // barrier-A flags, stride 16 ints (64B)
    int* FB = FLAGS + 4096;           // barrier-B flags

    // resident weights -> LDS (pre-kernel data: normal cached loads are safe)
    {
        const float4* s4 = (const float4*)(layer ? (WB1 + (size_t)w * (3 * 32 * 512))
                                                 : (WB0 + (size_t)w * (3 * 48 * 512)));
        float4* d4 = (float4*)sB;
        const int n = layer ? (3 * 32 * 64) : (3 * 48 * 64);
        for (int i = tid; i < n; i += 256) d4[i] = s4[i];
    }
    if (tid < 48) {
        int ct = tid >> 4, r = tid & 15;
        int gate = 2 * ct + (r >> 3);
        sBias[tid] = (layer ? b1 : b0)[gate * 1024 + j0 + (r & 7)];
    }
    float c0 = 0.f, c1 = 0.f;   // persistent cell state: (m_u, j0 + pr4*2 + {0,1})
    __syncthreads();

    for (int s = 0; s <= 256; ++s) {
        const int active = layer ? (s >= 1) : (s < 256);
        const int t = layer ? (s - 1) : s;
        const int hr = (s + 2) % 3;               // H0 read slot = h0(s-1)
        float* PARTs = PARTS + (size_t)s * 32768; // fresh PART slot for step s

        f32x4 acc[2][3];
        if (active) {
            // ---------- GEMM (K-split across wave pairs) ----------
#pragma unroll
            for (int r = 0; r < 2; ++r)
#pragma unroll
                for (int c = 0; c < 3; ++c) { f32x4 z = {0.f,0.f,0.f,0.f}; acc[r][c] = z; }

            const f16* h0r = H0P + (size_t)hr * 65536;
            const int abase = rtp * 1024 + lane * 8;

            if (layer == 0) {
                if (kh == 0) {
                    const f16* A1 = XP + (size_t)t * 32768;
#pragma unroll 8
                    for (int kt = 0; kt < 16; ++kt) {
                        const f16* ap = A1 + (size_t)kt * 2048 + abase;
                        f16x8 a0 = *(const f16x8*)ap;          // XP: pre-kernel, cached
                        f16x8 a1 = *(const f16x8*)(ap + 512);
#pragma unroll
                        for (int ct = 0; ct < 3; ++ct) {
                            f16x8 b = *(const f16x8*)(sB + ((size_t)(ct * 48 + kt) * 64 + lane) * 8);
                            acc[0][ct] = __builtin_amdgcn_mfma_f32_16x16x32_f16(a0, b, acc[0][ct], 0, 0, 0);
                            acc[1][ct] = __builtin_amdgcn_mfma_f32_16x16x32_f16(a1, b, acc[1][ct], 0, 0, 0);
                        }
                    }
#pragma unroll 8
                    for (int kt = 0; kt < 8; ++kt) {
                        const f16* ap = h0r + (size_t)kt * 2048 + abase;
                        f16x8 a0 = ld_frag(ap);                // H: intra-kernel, sc1
                        f16x8 a1 = ld_frag(ap + 512);
#pragma unroll
                        for (int ct = 0; ct < 3; ++ct) {
                            f16x8 b = *(const f16x8*)(sB + ((size_t)(ct * 48 + 16 + kt) * 64 + lane) * 8);
                            acc[0][ct] = __builtin_amdgcn_mfma_f32_16x16x32_f16(a0, b, acc[0][ct], 0, 0, 0);
                            acc[1][ct] = __builtin_amdgcn_mfma_f32_16x16x32_f16(a1, b, acc[1][ct], 0, 0, 0);
                        }
                    }
                } else {
#pragma unroll 8
                    for (int kt = 8; kt < 32; ++kt) {
                        const f16* ap = h0r + (size_t)kt * 2048 + abase;
                        f16x8 a0 = ld_frag(ap);
                        f16x8 a1 = ld_frag(ap + 512);
#pragma unroll
                        for (int ct = 0; ct < 3; ++ct) {
                            f16x8 b = *(const f16x8*)(sB + ((size_t)(ct * 48 + 16 + kt) * 64 + lane) * 8);
                            acc[0][ct] = __builtin_amdgcn_mfma_f32_16x16x32_f16(a0, b, acc[0][ct], 0, 0, 0);
                            acc[1][ct] = __builtin_amdgcn_mfma_f32_16x16x32_f16(a1, b, acc[1][ct], 0, 0, 0);
                        }
                    }
                }
            } else {
                if (kh == 0) {
                    const f16* BS = WS1 + (size_t)w * (3 * 32 * 512);  // pre-kernel, cached
#pragma unroll 8
                    for (int kt = 0; kt < 32; ++kt) {
                        const f16* ap = h0r + (size_t)kt * 2048 + abase;
                        f16x8 a0 = ld_frag(ap);
                        f16x8 a1 = ld_frag(ap + 512);
#pragma unroll
                        for (int ct = 0; ct < 3; ++ct) {
                            f16x8 b = *(const f16x8*)(BS + ((size_t)(ct * 32 + kt) * 64 + lane) * 8);
                            acc[0][ct] = __builtin_amdgcn_mfma_f32_16x16x32_f16(a0, b, acc[0][ct], 0, 0, 0);
                            acc[1][ct] = __builtin_amdgcn_mfma_f32_16x16x32_f16(a1, b, acc[1][ct], 0, 0, 0);
                        }
                    }
                } else {
                    const f16* h1r = H1P + (size_t)(s & 1) * 65536;    // h1(s-2)
#pragma unroll 8
                    for (int kt = 0; kt < 32; ++kt) {
                        const f16* ap = h1r + (size_t)kt * 2048 + abase;
                        f16x8 a0 = ld_frag(ap);
                        f16x8 a1 = ld_frag(ap + 512);
#pragma unroll
                        for (int ct = 0; ct < 3; ++ct) {
                            f16x8 b = *(const f16x8*)(sB + ((size_t)(ct * 32 + kt) * 64 + lane) * 8);
                            acc[0][ct] = __builtin_amdgcn_mfma_f32_16x16x32_f16(a0, b, acc[0][ct], 0, 0, 0);
                            acc[1][ct] = __builtin_amdgcn_mfma_f32_16x16x32_f16(a1, b, acc[1][ct], 0, 0, 0);
                        }
                    }
                }
            }
            // epilogue phase 1: kh=1 waves store partials (plain, disjoint rows)
            if (kh == 1) {
                const int mq = ((lane >> 4) << 2);
                const int colb = lane & 15;
#pragma unroll
                for (int r = 0; r < 2; ++r) {
                    int mrow = rtp * 32 + r * 16 + mq;
#pragma unroll
                    for (int ct = 0; ct < 3; ++ct) {
                        int col = ct * 16 + colb;
#pragma unroll
                        for (int q = 0; q < 4; ++q)
                            sZ[(mrow + q) * 49 + col] = acc[r][ct][q];
                    }
                }
            }
        }
        __syncthreads();   // kh1 partials visible
        if (active && kh == 0) {
            // epilogue phase 2: kh=0 waves RMW-add own acc + partial + bias
            const int mq = ((lane >> 4) << 2);
            const int colb = lane & 15;
#pragma unroll
            for (int r = 0; r < 2; ++r) {
                int mrow = rtp * 32 + r * 16 + mq;
#pragma unroll
                for (int ct = 0; ct < 3; ++ct) {
                    int col = ct * 16 + colb;
                    float bias = sBias[col];
#pragma unroll
                    for (int q = 0; q < 4; ++q) {
                        int idx = (mrow + q) * 49 + col;
                        sZ[idx] = sZ[idx] + acc[r][ct][q] + bias;
                    }
                }
            }
        }
        __syncthreads();

        if (active && tid < 128) {
            // local scan: exp + inclusive cumsum over 8 cols (g = f~ or i~)
            int g = tid >> 6, m = tid & 63;
            float run = 0.f;
            float* zp = sZ + m * 49 + 32 + g * 8;
#pragma unroll
            for (int jj = 0; jj < 8; ++jj) {
                float e = __expf(zp[jj]);
                run += e;
                zp[jj] = run;
            }
            __hip_atomic_store(&PARTs[((size_t)(layer * 2 + g) * 128 + w) * 64 + m], run,
                               __ATOMIC_RELAXED, AGENT);
        }

        // ---------- barrier A (layer-local, flag-based, fence-free) ----------
        __syncthreads();   // implicit vmcnt(0): all waves' sc1 stores at coherence point
        if (tid == 0)
            __hip_atomic_store(&FA[wg * 16], s + 1, __ATOMIC_RELAXED, AGENT);
        if (tid < 128) {
            const int* fp = &FA[(layer * 128 + tid) * 16];
            while (__hip_atomic_load(fp, __ATOMIC_RELAXED, AGENT) < s + 1) {}
        }
        __syncthreads();

        if (active) {
            // global prefix/total, half-split across the 4 waves.
            // PART slot is fresh this step: plain cached loads (L2-serviced).
            int g = pr4 & 1, half = pr4 >> 1;
            const float* pp = PARTs + ((size_t)(layer * 2 + g) * 128 + half * 64) * 64 + m_u;
            float pref = 0.f, tot = 0.f;
            int wrel = w - half * 64;
#pragma unroll 32
            for (int w2 = 0; w2 < 64; ++w2) {
                float v = pp[(size_t)w2 * 64];
                tot += v;
                pref += (w2 < wrel) ? v : 0.f;
            }
            float* q = sPfx + ((size_t)(m_u * 2 + g) * 2 + half) * 2;
            q[0] = pref; q[1] = tot;
        }
        __syncthreads();
        if (active && tid < 128) {
            int g = tid >> 6, m = tid & 63;
            float* q = sPfx + (size_t)(m * 2 + g) * 4;
            sScl[m * 4 + g * 2]     = q[0] + q[2];
            sScl[m * 4 + g * 2 + 1] = 1.0f / (q[1] + q[3]);
        }
        __syncthreads();

        if (active) {
            // ---------- gate math + state update (2 cols/thread) ----------
            float pf = sScl[m_u * 4 + 0], rf = sScl[m_u * 4 + 1];
            float pi = sScl[m_u * 4 + 2], ri = sScl[m_u * 4 + 3];
            int zb = m_u * 49;
            float cc[2] = {c0, c1}, hh[2];
#pragma unroll
            for (int q = 0; q < 2; ++q) {
                int jj = pr4 * 2 + q;
                float zi = sZ[zb + jj];
                float zf = sZ[zb + 8 + jj];
                float zg = sZ[zb + 16 + jj];
                float zo = sZ[zb + 24 + jj];
                float cft = sZ[zb + 32 + jj];
                float cit = sZ[zb + 40 + jj];
                float ftil = (pf + cft) * rf;
                float itil = 1.0f - (pi + cit) * ri;
                float om = ftil * itil;
                float fi = fast_sigmoid(zf);
                float ii = fast_sigmoid(zi);
                float oo = fast_sigmoid(zo);
                float ch = fast_tanh(zg);
                float fh = fi * om + (ftil - om);
                float ih = ii * om + (itil - om);
                float cn = fh * cc[q] + ih * ch;
                cc[q] = cn;
                hh[q] = oo * fast_tanh(cn);
            }
            c0 = cc[0]; c1 = cc[1];

            // publish h as A-fragments (fp16, sc1 write-through)
            int jfull = j0 + pr4 * 2;
            int ktp = jfull >> 5;
            int quad = (jfull >> 3) & 3;
            int i0 = jfull & 7;
            f16* HP = layer ? (H1P + (size_t)((s + 1) & 1) * 65536)
                            : (H0P + (size_t)(s % 3) * 65536);
            union { f16x2 h; int i; } hu;
            hu.h[0] = (f16)hh[0]; hu.h[1] = (f16)hh[1];
            __hip_atomic_store(
                (int*)(HP + ((size_t)(ktp * 4 + (m_u >> 4)) * 64 + (quad * 16 + (m_u & 15))) * 8 + i0),
                hu.i, __ATOMIC_RELAXED, AGENT);

            if (layer)
                *(float2*)(out + (size_t)t * 65536 + (size_t)m_u * 1024 + jfull) = make_float2(hh[0], hh[1]);
            if (t == 255) {
                *(float2*)(out + 16777216 + (size_t)layer * 65536 + (size_t)m_u * 1024 + jfull) = make_float2(hh[0], hh[1]);
                *(float2*)(out + 16908288 + (size_t)layer * 65536 + (size_t)m_u * 1024 + jfull) = make_float2(cc[0], cc[1]);
            }
        }

        // ---------- barrier B (split by layer, pipeline slack, fence-free) ----------
        if (s < 256) {
            __syncthreads();   // drains all waves' h sc1 stores
            if (tid == 0)
                __hip_atomic_store(&FB[wg * 16], s + 1, __ATOMIC_RELAXED, AGENT);
            if (layer == 0) {
                if (tid < 128) {
                    const int* fp = &FB[tid * 16];
                    while (__hip_atomic_load(fp, __ATOMIC_RELAXED, AGENT) < s + 1) {}
                } else {
                    // anti-overwrite: layer1 must have finished GEMM of step s-1
                    const int* fp = &FA[tid * 16];
                    while (__hip_atomic_load(fp, __ATOMIC_RELAXED, AGENT) < s) {}
                }
            } else {
                const int* fp = &FB[tid * 16];
                while (__hip_atomic_load(fp, __ATOMIC_RELAXED, AGENT) < s + 1) {}
            }
            __syncthreads();
        }
    }
}

// ---------------- launch ----------------
extern "C" void kernel_launch(void* const* d_in, const int* in_sizes, int n_in,
                              void* d_out, int out_size, void* d_ws, size_t ws_size,
                              hipStream_t stream) {
    const float* x  = (const float*)d_in[0];
    const float* W0 = (const float*)d_in[1];
    const float* b0 = (const float*)d_in[2];
    const float* W1 = (const float*)d_in[3];
    const float* b1 = (const float*)d_in[4];
    float* out = (float*)d_out;

    char* ws = (char*)d_ws;
    f16* WB0     = (f16*)(ws + 0);           // 18874368
    f16* WB1     = (f16*)(ws + 18874368);    // 12582912
    f16* WS1     = (f16*)(ws + 31457280);    // 12582912
    f16* XP      = (f16*)(ws + 44040192);    // 16777216
    f16* H0P     = (f16*)(ws + 60817408);    // 3 x 131072
    f16* H1P     = (f16*)(ws + 61210624);    // 2 x 131072
    int* FLAGS   = (int*)(ws + 61603840);    // 32768
    float* PARTS = (float*)(ws + 61636608);  // 257 x 131072 = 33685504 (end ~95.3 MB,
                                             // within the 128.35 MB proven by r5/r8)

    hipMemsetAsync(H0P, 0, 393216, stream);
    hipMemsetAsync(H1P, 0, 262144, stream);
    hipMemsetAsync(FLAGS, 0, 32768, stream);

    {   int n = 128 * 3 * 48 * 64;
        onlstm_pack_w<<<(n + 255) / 256, 256, 0, stream>>>(W0, WB0, 48, 0); }
    {   int n = 128 * 3 * 32 * 64;
        onlstm_pack_w<<<(n + 255) / 256, 256, 0, stream>>>(W1, WB1, 32, 1024); }
    {   int n = 128 * 3 * 32 * 64;
        onlstm_pack_w<<<(n + 255) / 256, 256, 0, stream>>>(W1, WS1, 32, 0); }
    {   int n = 256 * 16 * 4 * 64;
        onlstm_pack_x<<<(n + 255) / 256, 256, 0, stream>>>(x, XP); }

    const int smem_bytes = 163328;
    hipFuncSetAttribute((const void*)onlstm_main,
                        hipFuncAttributeMaxDynamicSharedMemorySize, smem_bytes);
    onlstm_main<<<NWG, 256, smem_bytes, stream>>>(WB0, WB1, WS1, XP, H0P, H1P,
                                                  PARTS, FLAGS, b0, b1, out);
}